// Round 13
// baseline (33.126 us; speedup 1.0000x reference)
//
#include <hip/hip_runtime.h>

constexpr int Bn  = 8;
constexpr int Hn  = 512;
constexpr int Wn  = 512;
constexpr int HWn = Hn * Wn;        // 262144
constexpr int NPIX = Bn * HWn;      // 2097152
constexpr int NBLK = 2048;          // 4 waves/block; wave = half-row, 4 px/lane
constexpr int NWAVE = 8192;         // one partial-set per wave
constexpr float BIGE = 1e30f;       // missing neighbor: vote==0 exactly in f32 logs

typedef float f4 __attribute__((ext_vector_type(4)));
typedef int   i4 __attribute__((ext_vector_type(4)));

// channel order: [down_right, down, down_left, right, left, up_right, up, up_left]
// conn_t[i][r,c] = t[r,c]*t[r-dy_i,c-dx_i]; vote[i][r,c] = p_i[r,c]*p_{7-i}[r-dy_i,c-dx_i]
// dy = {1,1,1,0,0,-1,-1,-1}, dx = {1,0,-1,1,-1,1,0,-1}

__device__ __forceinline__ f4 shrf(f4 v, float edge, int lane) {   // value at col c-1
    float u = __shfl_up(v.w, 1, 64);
    if (lane == 0) u = edge;
    return (f4){u, v.x, v.y, v.z};
}
__device__ __forceinline__ f4 shlf(f4 v, float edge, int lane) {   // value at col c+1
    float d = __shfl_down(v.x, 1, 64);
    if (lane == 63) d = edge;
    return (f4){v.y, v.z, v.w, d};
}
__device__ __forceinline__ i4 shri(i4 v, int edge, int lane) {
    int u = __shfl_up(v.w, 1, 64);
    if (lane == 0) u = edge;
    return (i4){u, v.x, v.y, v.z};
}
__device__ __forceinline__ i4 shli(i4 v, int edge, int lane) {
    int d = __shfl_down(v.x, 1, 64);
    if (lane == 63) d = edge;
    return (i4){v.y, v.z, v.w, d};
}

__global__ __launch_bounds__(256) void connect_loss_main(
    const float* __restrict__ cm,   // (B,8,H,W) f32
    const int*   __restrict__ tg,   // (B,1,H,W) i32
    float*       __restrict__ ws)   // per-wave partials ws[k*NWAVE + gw]
{
    const int lane = threadIdx.x & 63;
    const int gw   = blockIdx.x * 4 + (threadIdx.x >> 6);    // half-row id, 0..8191
    const int half = gw & 1;
    const int rowIdx = gw >> 1;                              // 0..4095
    const int r  = rowIdx & (Hn - 1);
    const int b  = rowIdx >> 9;
    const int w0 = half * 256;
    const int c0 = w0 + lane * 4;

    const float* cmb  = cm + (size_t)b * 8 * HWn;
    const int*   tgb  = tg + (size_t)b * HWn;
    const float* rowp = cmb + (size_t)r * Wn;
    const float* rowm = rowp - Wn;                           // valid iff hasUp
    const float* rowq = rowp + Wn;                           // valid iff hasDn
    const bool hasUp = (r > 0), hasDn = (r < Hn - 1);        // wave-uniform

    // ---------- issue own-channel loads FIRST ----------
    f4 xo0 = *(const f4*)(rowp + (size_t)0 * HWn + c0);
    f4 xo1 = *(const f4*)(rowp + (size_t)1 * HWn + c0);
    f4 xo2 = *(const f4*)(rowp + (size_t)2 * HWn + c0);
    f4 xo3 = *(const f4*)(rowp + (size_t)3 * HWn + c0);
    f4 xo4 = *(const f4*)(rowp + (size_t)4 * HWn + c0);
    f4 xo5 = *(const f4*)(rowp + (size_t)5 * HWn + c0);
    f4 xo6 = *(const f4*)(rowp + (size_t)6 * HWn + c0);
    f4 xo7 = *(const f4*)(rowp + (size_t)7 * HWn + c0);

    // ---------- then neighbor/target/edge loads ----------
    f4 xm5 = {0,0,0,0}, xm6 = {0,0,0,0}, xm7 = {0,0,0,0};
    f4 xp0 = {0,0,0,0}, xp1 = {0,0,0,0}, xp2 = {0,0,0,0};
    i4 tm = {0,0,0,0}, tp = {0,0,0,0};
    if (hasUp) {
        xm5 = *(const f4*)(rowm + (size_t)5 * HWn + c0);
        xm6 = *(const f4*)(rowm + (size_t)6 * HWn + c0);
        xm7 = *(const f4*)(rowm + (size_t)7 * HWn + c0);
        tm  = *(const i4*)(tgb + (size_t)(r - 1) * Wn + c0);
    }
    if (hasDn) {
        xp0 = *(const f4*)(rowq + (size_t)0 * HWn + c0);
        xp1 = *(const f4*)(rowq + (size_t)1 * HWn + c0);
        xp2 = *(const f4*)(rowq + (size_t)2 * HWn + c0);
        tp  = *(const i4*)(tgb + (size_t)(r + 1) * Wn + c0);
    }
    i4 tt = *(const i4*)(tgb + (size_t)r * Wn + c0);

    float lLt = 1e9f, lLm = 1e9f, lLp = 1e9f, lRt = 1e9f, lRm = 1e9f, lRp = 1e9f;
    int   tLt = 0, tLm = 0, tLp = 0, tRt = 0, tRm = 0, tRp = 0;
    if (half == 1) {                                         // left neighbor col = 255
        lLt = rowp[(size_t)4 * HWn + 255];  tLt = tgb[(size_t)r * Wn + 255];
        if (hasUp) { lLm = rowm[(size_t)7 * HWn + 255]; tLm = tgb[(size_t)(r - 1) * Wn + 255]; }
        if (hasDn) { lLp = rowq[(size_t)2 * HWn + 255]; tLp = tgb[(size_t)(r + 1) * Wn + 255]; }
    } else {                                                 // right neighbor col = 256
        lRt = rowp[(size_t)3 * HWn + 256];  tRt = tgb[(size_t)r * Wn + 256];
        if (hasUp) { lRm = rowm[(size_t)5 * HWn + 256]; tRm = tgb[(size_t)(r - 1) * Wn + 256]; }
        if (hasDn) { lRp = rowq[(size_t)0 * HWn + 256]; tRp = tgb[(size_t)(r + 1) * Wn + 256]; }
    }

    // lock load-issue placement: nothing may sink below this point
    asm volatile("" ::: "memory");

    // ---------- pin A: own channels only -> partial waitcnt, neighbors in flight ----------
    asm volatile("" : "+v"(xo0), "+v"(xo1), "+v"(xo2), "+v"(xo3),
                      "+v"(xo4), "+v"(xo5), "+v"(xo6), "+v"(xo7));

    f4 xo[8] = {xo0, xo1, xo2, xo3, xo4, xo5, xo6, xo7};
    f4 eo[8];
    #pragma unroll
    for (int ch = 0; ch < 8; ++ch) {
        #pragma unroll
        for (int j = 0; j < 4; ++j) eo[ch][j] = __expf(-xo[ch][j]);
    }
    // own-only: sum_i log p_i = -log prod_i (1+e_i)
    float slog = 0.f;
    #pragma unroll
    for (int j = 0; j < 4; ++j) {
        const float Pr = (((1.f + eo[0][j]) * (1.f + eo[1][j])) *
                          ((1.f + eo[2][j]) * (1.f + eo[3][j]))) *
                         (((1.f + eo[4][j]) * (1.f + eo[5][j])) *
                          ((1.f + eo[6][j]) * (1.f + eo[7][j])));
        slog += __logf(Pr);
    }

    // ---------- pin B: neighbors + targets + edge scalars ----------
    asm volatile("" : "+v"(xm5), "+v"(xm6), "+v"(xm7),
                      "+v"(xp0), "+v"(xp1), "+v"(xp2),
                      "+v"(tt), "+v"(tm), "+v"(tp),
                      "+v"(lLt), "+v"(lLm), "+v"(lLp),
                      "+v"(lRt), "+v"(lRm), "+v"(lRp));

    const float eLt = (half == 1) ? __expf(-lLt) : BIGE;
    const float eLm = (half == 1 && hasUp) ? __expf(-lLm) : BIGE;
    const float eLp = (half == 1 && hasDn) ? __expf(-lLp) : BIGE;
    const float eRt = (half == 0) ? __expf(-lRt) : BIGE;
    const float eRm = (half == 0 && hasUp) ? __expf(-lRm) : BIGE;
    const float eRp = (half == 0 && hasDn) ? __expf(-lRp) : BIGE;

    f4 em5, em6, em7, ep0, ep1, ep2;
    if (hasUp) {
        #pragma unroll
        for (int j = 0; j < 4; ++j) {
            em5[j] = __expf(-xm5[j]); em6[j] = __expf(-xm6[j]); em7[j] = __expf(-xm7[j]);
        }
    } else em5 = em6 = em7 = (f4){BIGE, BIGE, BIGE, BIGE};
    if (hasDn) {
        #pragma unroll
        for (int j = 0; j < 4; ++j) {
            ep0[j] = __expf(-xp0[j]); ep1[j] = __expf(-xp1[j]); ep2[j] = __expf(-xp2[j]);
        }
    } else ep0 = ep1 = ep2 = (f4){BIGE, BIGE, BIGE, BIGE};

    // ---------- pair loop in E-space: E = e + en + e*en; vote = 1/(1+E) ----------
    f4 Emin = {3.4e38f, 3.4e38f, 3.4e38f, 3.4e38f};
    f4 Emax = {0.f, 0.f, 0.f, 0.f};
    int cnt[4] = {0, 0, 0, 0};
    float sx = 0.f;

    #define PAIR(i, ENX, TNX)                                            \
    {                                                                    \
        const f4 enx = (ENX);                                            \
        const i4 tnx = (TNX);                                            \
        _Pragma("unroll")                                                \
        for (int j = 0; j < 4; ++j) {                                    \
            const float E = __builtin_fmaf(eo[i][j], enx[j],             \
                                           eo[i][j] + enx[j]);           \
            Emin[j] = fminf(Emin[j], E);                                 \
            Emax[j] = fmaxf(Emax[j], E);                                 \
            const bool ct = (tt[j] != 0) & (tnx[j] != 0);                \
            cnt[j] += ct ? 1 : 0;                                        \
            sx += ct ? 0.f : xo[i][j];                                   \
        }                                                                \
    }
    PAIR(3, shrf(eo[4], eLt, lane), shri(tt, tLt, lane))   // ch4 @ (r, c-1)
    PAIR(4, shlf(eo[3], eRt, lane), shli(tt, tRt, lane))   // ch3 @ (r, c+1)
    PAIR(0, shrf(em7, eLm, lane),   shri(tm, tLm, lane))   // ch7 @ (r-1, c-1)
    PAIR(1, em6,                    tm)                    // ch6 @ (r-1, c)
    PAIR(2, shlf(em5, eRm, lane),   shli(tm, tRm, lane))   // ch5 @ (r-1, c+1)
    PAIR(5, shrf(ep2, eLp, lane),   shri(tp, tLp, lane))   // ch2 @ (r+1, c-1)
    PAIR(6, ep1,                    tp)                    // ch1 @ (r+1, c)
    PAIR(7, shlf(ep0, eRp, lane),   shli(tp, tRp, lane))   // ch0 @ (r+1, c+1)
    #undef PAIR

    // ---------- per-pixel tail: 2 logs per pixel ----------
    float s_bimap = 0.f, s_edge = 0.f, s_inter = 0.f, s_fp = 0.f, s_t = 0.f;
    #pragma unroll
    for (int j = 0; j < 4; ++j) {
        const float Em = Emin[j], EM = Emax[j];
        const float vm = __builtin_amdgcn_rcpf(1.0f + Em);       // vmax
        s_bimap += __logf((tt[j] != 0) ? vm : Em * vm);          // t?log(vmax):log(1-vmax)
        const float vM = __builtin_amdgcn_rcpf(1.0f + EM);
        const bool eg = (cnt[j] > 0) & (cnt[j] < 8);
        s_edge += __logf(eg ? EM * vM : 1.0f);                   // log(1-vmin) on edge px
        s_fp    += vm;
        s_inter += (tt[j] != 0) ? vm : 0.f;
        s_t     += (float)tt[j];
    }

    // ---------- wave tree reduce, per-wave plain store (no LDS, no barrier) ----------
    float vals[6] = {slog + sx, s_bimap, s_edge, s_inter, s_fp, s_t};
    #pragma unroll
    for (int k = 0; k < 6; ++k) {
        float v = vals[k];
        #pragma unroll
        for (int off = 32; off > 0; off >>= 1) v += __shfl_down(v, off, 64);
        vals[k] = v;
    }
    if (lane == 0) {
        #pragma unroll
        for (int k = 0; k < 6; ++k) ws[k * NWAVE + gw] = vals[k];
    }
}

// single-block reduce of 6 x NWAVE partials + final loss
__global__ __launch_bounds__(256) void connect_loss_reduce(
    const float* __restrict__ ws, float* __restrict__ out)
{
    float acc[6];
    #pragma unroll
    for (int k = 0; k < 6; ++k) {
        const f4* p = (const f4*)(ws + k * NWAVE + threadIdx.x * 32);
        float s = 0.f;
        #pragma unroll
        for (int u = 0; u < 8; ++u) {                   // 256*32 = 8192 = NWAVE
            const f4 a = p[u];
            s += (a.x + a.y) + (a.z + a.w);
        }
        acc[k] = s;
    }
    #pragma unroll
    for (int k = 0; k < 6; ++k) {
        float v = acc[k];
        #pragma unroll
        for (int off = 32; off > 0; off >>= 1) v += __shfl_down(v, off, 64);
        acc[k] = v;
    }
    __shared__ float bs[6];
    if (threadIdx.x < 6) bs[threadIdx.x] = 0.0f;
    __syncthreads();
    if ((threadIdx.x & 63) == 0) {
        #pragma unroll
        for (int k = 0; k < 6; ++k) atomicAdd(&bs[k], acc[k]);
    }
    __syncthreads();
    if (threadIdx.x == 0) {
        // bs[0] = sum(log(1+e)) + sum((1-ct)x) = -sum(conn BCE log-terms)
        const float conn_l  =  bs[0] / (float)(8 * NPIX);
        const float bimap_l = -bs[1] / (float)NPIX;
        const float edge_l  = -bs[2] / (float)NPIX;
        const float dice_l  = 1.0f - (2.0f * bs[3] + 1.0f) / (bs[4] + bs[5] + 1.0f);
        out[0] = conn_l + bimap_l + edge_l + dice_l;
    }
}

extern "C" void kernel_launch(void* const* d_in, const int* in_sizes, int n_in,
                              void* d_out, int out_size, void* d_ws, size_t ws_size,
                              hipStream_t stream) {
    const float* cm = (const float*)d_in[0];      // c_map (B,8,H,W) f32
    const int*   tg = (const int*)d_in[3];        // target (B,1,H,W) i32
    float* ws  = (float*)d_ws;                    // 6*NWAVE floats (192 KB)
    float* out = (float*)d_out;

    connect_loss_main<<<NBLK, 256, 0, stream>>>(cm, tg, ws);
    connect_loss_reduce<<<1, 256, 0, stream>>>(ws, out);
}

// Round 14
// 32.863 us; speedup vs baseline: 1.0080x; 1.0080x over previous
//
#include <hip/hip_runtime.h>

constexpr int Bn  = 8;
constexpr int Hn  = 512;
constexpr int Wn  = 512;
constexpr int HWn = Hn * Wn;        // 262144
constexpr int NPIX = Bn * HWn;      // 2097152
constexpr int NBLK = 2048;          // 4 waves/block; wave = half-row, 4 px/lane
constexpr int NWAVE = 8192;         // one partial-set per wave
constexpr float BIGE = 1e30f;       // missing neighbor: vote==0 exactly in f32 logs

typedef float f4 __attribute__((ext_vector_type(4)));
typedef int   i4 __attribute__((ext_vector_type(4)));

// channel order: [down_right, down, down_left, right, left, up_right, up, up_left]
// conn_t[i][r,c] = t[r,c]*t[r-dy_i,c-dx_i]; vote[i][r,c] = p_i[r,c]*p_{7-i}[r-dy_i,c-dx_i]
// dy = {1,1,1,0,0,-1,-1,-1}, dx = {1,0,-1,1,-1,1,0,-1}

__device__ __forceinline__ f4 shrf(f4 v, float edge, int lane) {   // value at col c-1
    float u = __shfl_up(v.w, 1, 64);
    if (lane == 0) u = edge;
    return (f4){u, v.x, v.y, v.z};
}
__device__ __forceinline__ f4 shlf(f4 v, float edge, int lane) {   // value at col c+1
    float d = __shfl_down(v.x, 1, 64);
    if (lane == 63) d = edge;
    return (f4){v.y, v.z, v.w, d};
}
__device__ __forceinline__ i4 shri(i4 v, int edge, int lane) {
    int u = __shfl_up(v.w, 1, 64);
    if (lane == 0) u = edge;
    return (i4){u, v.x, v.y, v.z};
}
__device__ __forceinline__ i4 shli(i4 v, int edge, int lane) {
    int d = __shfl_down(v.x, 1, 64);
    if (lane == 63) d = edge;
    return (i4){v.y, v.z, v.w, d};
}

__global__ __launch_bounds__(256) void connect_loss_main(
    const float* __restrict__ cm,   // (B,8,H,W) f32
    const int*   __restrict__ tg,   // (B,1,H,W) i32
    float*       __restrict__ ws)   // per-wave partials ws[k*NWAVE + gw]
{
    const int lane = threadIdx.x & 63;
    const int gw   = blockIdx.x * 4 + (threadIdx.x >> 6);    // half-row id, 0..8191
    const int half = gw & 1;
    const int rowIdx = gw >> 1;                              // 0..4095
    const int r  = rowIdx & (Hn - 1);
    const int b  = rowIdx >> 9;
    const int w0 = half * 256;
    const int c0 = w0 + lane * 4;

    const float* cmb  = cm + (size_t)b * 8 * HWn;
    const int*   tgb  = tg + (size_t)b * HWn;
    const float* rowp = cmb + (size_t)r * Wn;
    const float* rowm = rowp - Wn;                           // valid iff hasUp
    const float* rowq = rowp + Wn;                           // valid iff hasDn
    const bool hasUp = (r > 0), hasDn = (r < Hn - 1);        // wave-uniform

    // ---------- issue the ENTIRE load batch ----------
    f4 xo0 = *(const f4*)(rowp + (size_t)0 * HWn + c0);
    f4 xo1 = *(const f4*)(rowp + (size_t)1 * HWn + c0);
    f4 xo2 = *(const f4*)(rowp + (size_t)2 * HWn + c0);
    f4 xo3 = *(const f4*)(rowp + (size_t)3 * HWn + c0);
    f4 xo4 = *(const f4*)(rowp + (size_t)4 * HWn + c0);
    f4 xo5 = *(const f4*)(rowp + (size_t)5 * HWn + c0);
    f4 xo6 = *(const f4*)(rowp + (size_t)6 * HWn + c0);
    f4 xo7 = *(const f4*)(rowp + (size_t)7 * HWn + c0);

    f4 xm5 = {0,0,0,0}, xm6 = {0,0,0,0}, xm7 = {0,0,0,0};
    f4 xp0 = {0,0,0,0}, xp1 = {0,0,0,0}, xp2 = {0,0,0,0};
    i4 tm = {0,0,0,0}, tp = {0,0,0,0};
    if (hasUp) {
        xm5 = *(const f4*)(rowm + (size_t)5 * HWn + c0);
        xm6 = *(const f4*)(rowm + (size_t)6 * HWn + c0);
        xm7 = *(const f4*)(rowm + (size_t)7 * HWn + c0);
        tm  = *(const i4*)(tgb + (size_t)(r - 1) * Wn + c0);
    }
    if (hasDn) {
        xp0 = *(const f4*)(rowq + (size_t)0 * HWn + c0);
        xp1 = *(const f4*)(rowq + (size_t)1 * HWn + c0);
        xp2 = *(const f4*)(rowq + (size_t)2 * HWn + c0);
        tp  = *(const i4*)(tgb + (size_t)(r + 1) * Wn + c0);
    }
    i4 tt = *(const i4*)(tgb + (size_t)r * Wn + c0);

    // wave-uniform edge-column raw values (logits; exp applied after the pin)
    float lLt = 1e9f, lLm = 1e9f, lLp = 1e9f, lRt = 1e9f, lRm = 1e9f, lRp = 1e9f;
    int   tLt = 0, tLm = 0, tLp = 0, tRt = 0, tRm = 0, tRp = 0;
    if (half == 1) {                                         // left neighbor col = 255
        lLt = rowp[(size_t)4 * HWn + 255];  tLt = tgb[(size_t)r * Wn + 255];
        if (hasUp) { lLm = rowm[(size_t)7 * HWn + 255]; tLm = tgb[(size_t)(r - 1) * Wn + 255]; }
        if (hasDn) { lLp = rowq[(size_t)2 * HWn + 255]; tLp = tgb[(size_t)(r + 1) * Wn + 255]; }
    } else {                                                 // right neighbor col = 256
        lRt = rowp[(size_t)3 * HWn + 256];  tRt = tgb[(size_t)r * Wn + 256];
        if (hasUp) { lRm = rowm[(size_t)5 * HWn + 256]; tRm = tgb[(size_t)(r - 1) * Wn + 256]; }
        if (hasDn) { lRp = rowq[(size_t)0 * HWn + 256]; tRp = tgb[(size_t)(r + 1) * Wn + 256]; }
    }

    // single pin: all loads above must be materialized here -> full-batch issue,
    // ONE s_waitcnt, then pure compute (defeats IR-level load sinking)
    asm volatile("" : "+v"(xo0), "+v"(xo1), "+v"(xo2), "+v"(xo3),
                      "+v"(xo4), "+v"(xo5), "+v"(xo6), "+v"(xo7),
                      "+v"(xm5), "+v"(xm6), "+v"(xm7),
                      "+v"(xp0), "+v"(xp1), "+v"(xp2),
                      "+v"(tt), "+v"(tm), "+v"(tp),
                      "+v"(lLt), "+v"(lLm), "+v"(lLp),
                      "+v"(lRt), "+v"(lRm), "+v"(lRp));

    // ---------- e = exp(-x) ----------
    const float eLt = (half == 1) ? __expf(-lLt) : BIGE;
    const float eLm = (half == 1 && hasUp) ? __expf(-lLm) : BIGE;
    const float eLp = (half == 1 && hasDn) ? __expf(-lLp) : BIGE;
    const float eRt = (half == 0) ? __expf(-lRt) : BIGE;
    const float eRm = (half == 0 && hasUp) ? __expf(-lRm) : BIGE;
    const float eRp = (half == 0 && hasDn) ? __expf(-lRp) : BIGE;

    f4 xo[8] = {xo0, xo1, xo2, xo3, xo4, xo5, xo6, xo7};
    f4 eo[8];
    #pragma unroll
    for (int ch = 0; ch < 8; ++ch) {
        #pragma unroll
        for (int j = 0; j < 4; ++j) eo[ch][j] = __expf(-xo[ch][j]);
    }
    f4 em5, em6, em7, ep0, ep1, ep2;
    if (hasUp) {
        #pragma unroll
        for (int j = 0; j < 4; ++j) {
            em5[j] = __expf(-xm5[j]); em6[j] = __expf(-xm6[j]); em7[j] = __expf(-xm7[j]);
        }
    } else em5 = em6 = em7 = (f4){BIGE, BIGE, BIGE, BIGE};
    if (hasDn) {
        #pragma unroll
        for (int j = 0; j < 4; ++j) {
            ep0[j] = __expf(-xp0[j]); ep1[j] = __expf(-xp1[j]); ep2[j] = __expf(-xp2[j]);
        }
    } else ep0 = ep1 = ep2 = (f4){BIGE, BIGE, BIGE, BIGE};

    // ---------- pair loop in E-space: E = e + en + e*en; vote = 1/(1+E) ----------
    f4 Emin = {3.4e38f, 3.4e38f, 3.4e38f, 3.4e38f};
    f4 Emax = {0.f, 0.f, 0.f, 0.f};
    int cnt[4] = {0, 0, 0, 0};
    float sx = 0.f;

    #define PAIR(i, ENX, TNX)                                            \
    {                                                                    \
        const f4 enx = (ENX);                                            \
        const i4 tnx = (TNX);                                            \
        _Pragma("unroll")                                                \
        for (int j = 0; j < 4; ++j) {                                    \
            const float E = __builtin_fmaf(eo[i][j], enx[j],             \
                                           eo[i][j] + enx[j]);           \
            Emin[j] = fminf(Emin[j], E);                                 \
            Emax[j] = fmaxf(Emax[j], E);                                 \
            const bool ct = (tt[j] != 0) & (tnx[j] != 0);                \
            cnt[j] += ct ? 1 : 0;                                        \
            sx += ct ? 0.f : xo[i][j];                                   \
        }                                                                \
    }
    PAIR(3, shrf(eo[4], eLt, lane), shri(tt, tLt, lane))   // ch4 @ (r, c-1)
    PAIR(4, shlf(eo[3], eRt, lane), shli(tt, tRt, lane))   // ch3 @ (r, c+1)
    PAIR(0, shrf(em7, eLm, lane),   shri(tm, tLm, lane))   // ch7 @ (r-1, c-1)
    PAIR(1, em6,                    tm)                    // ch6 @ (r-1, c)
    PAIR(2, shlf(em5, eRm, lane),   shli(tm, tRm, lane))   // ch5 @ (r-1, c+1)
    PAIR(5, shrf(ep2, eLp, lane),   shri(tp, tLp, lane))   // ch2 @ (r+1, c-1)
    PAIR(6, ep1,                    tp)                    // ch1 @ (r+1, c)
    PAIR(7, shlf(ep0, eRp, lane),   shli(tp, tRp, lane))   // ch0 @ (r+1, c+1)
    #undef PAIR

    // ---------- per-pixel tail: 3 logs per pixel ----------
    float s_logsx = sx, s_bimap = 0.f, s_edge = 0.f,
          s_inter = 0.f, s_fp = 0.f, s_t = 0.f;
    #pragma unroll
    for (int j = 0; j < 4; ++j) {
        // sum_i log p_i = -log prod_i (1+e_i)
        const float Pr = (((1.f + eo[0][j]) * (1.f + eo[1][j])) *
                          ((1.f + eo[2][j]) * (1.f + eo[3][j]))) *
                         (((1.f + eo[4][j]) * (1.f + eo[5][j])) *
                          ((1.f + eo[6][j]) * (1.f + eo[7][j])));
        s_logsx += __logf(Pr);

        const float Em = Emin[j], EM = Emax[j];
        const float vm = __builtin_amdgcn_rcpf(1.0f + Em);       // vmax
        s_bimap += __logf((tt[j] != 0) ? vm : Em * vm);          // t?log(vmax):log(1-vmax)
        const float vM = __builtin_amdgcn_rcpf(1.0f + EM);
        const bool eg = (cnt[j] > 0) & (cnt[j] < 8);
        s_edge += __logf(eg ? EM * vM : 1.0f);                   // log(1-vmin) on edge px
        s_fp    += vm;
        s_inter += (tt[j] != 0) ? vm : 0.f;
        s_t     += (float)tt[j];
    }

    // ---------- wave tree reduce + per-wave direct store (no LDS, no barriers) ----------
    float vals[6] = {s_logsx, s_bimap, s_edge, s_inter, s_fp, s_t};
    #pragma unroll
    for (int k = 0; k < 6; ++k) {
        float v = vals[k];
        #pragma unroll
        for (int off = 32; off > 0; off >>= 1) v += __shfl_down(v, off, 64);
        vals[k] = v;
    }
    if (lane == 0) {
        #pragma unroll
        for (int k = 0; k < 6; ++k) ws[k * NWAVE + gw] = vals[k];
    }
}

// single-block reduce of 6 x NWAVE partials + final loss
__global__ __launch_bounds__(256) void connect_loss_reduce(
    const float* __restrict__ ws, float* __restrict__ out)
{
    float acc[6];
    #pragma unroll
    for (int k = 0; k < 6; ++k) {
        const f4* p = (const f4*)(ws + k * NWAVE + threadIdx.x * 32);
        float s = 0.f;
        #pragma unroll
        for (int u = 0; u < 8; ++u) {                   // 256*32 = 8192 = NWAVE
            const f4 a = p[u];
            s += (a.x + a.y) + (a.z + a.w);
        }
        acc[k] = s;
    }
    #pragma unroll
    for (int k = 0; k < 6; ++k) {
        float v = acc[k];
        #pragma unroll
        for (int off = 32; off > 0; off >>= 1) v += __shfl_down(v, off, 64);
        acc[k] = v;
    }
    __shared__ float bs[6];
    if (threadIdx.x < 6) bs[threadIdx.x] = 0.0f;
    __syncthreads();
    if ((threadIdx.x & 63) == 0) {
        #pragma unroll
        for (int k = 0; k < 6; ++k) atomicAdd(&bs[k], acc[k]);
    }
    __syncthreads();
    if (threadIdx.x == 0) {
        // bs[0] = sum(log(1+e)) + sum((1-ct)x) = -sum(conn BCE log-terms)
        const float conn_l  =  bs[0] / (float)(8 * NPIX);
        const float bimap_l = -bs[1] / (float)NPIX;
        const float edge_l  = -bs[2] / (float)NPIX;
        const float dice_l  = 1.0f - (2.0f * bs[3] + 1.0f) / (bs[4] + bs[5] + 1.0f);
        out[0] = conn_l + bimap_l + edge_l + dice_l;
    }
}

extern "C" void kernel_launch(void* const* d_in, const int* in_sizes, int n_in,
                              void* d_out, int out_size, void* d_ws, size_t ws_size,
                              hipStream_t stream) {
    const float* cm = (const float*)d_in[0];      // c_map (B,8,H,W) f32
    const int*   tg = (const int*)d_in[3];        // target (B,1,H,W) i32
    float* ws  = (float*)d_ws;                    // 6*NWAVE floats (192 KB)
    float* out = (float*)d_out;

    connect_loss_main<<<NBLK, 256, 0, stream>>>(cm, tg, ws);
    connect_loss_reduce<<<1, 256, 0, stream>>>(ws, out);
}

// Round 15
// 27.010 us; speedup vs baseline: 1.2264x; 1.2167x over previous
//
#include <hip/hip_runtime.h>

constexpr int Bn  = 8;
constexpr int Hn  = 512;
constexpr int Wn  = 512;
constexpr int HWn = Hn * Wn;        // 262144
constexpr int NPIX = Bn * HWn;      // 2097152
constexpr int NBLK = 2048;          // 4 waves/block; wave = half-row, 4 px/lane
constexpr float BIGE = 1e30f;       // missing neighbor: vote==0 exactly in f32 logs

typedef float f4 __attribute__((ext_vector_type(4)));
typedef int   i4 __attribute__((ext_vector_type(4)));

// channel order: [down_right, down, down_left, right, left, up_right, up, up_left]
// conn_t[i][r,c] = t[r,c]*t[r-dy_i,c-dx_i]; vote[i][r,c] = p_i[r,c]*p_{7-i}[r-dy_i,c-dx_i]
// dy = {1,1,1,0,0,-1,-1,-1}, dx = {1,0,-1,1,-1,1,0,-1}

__device__ __forceinline__ f4 shrf(f4 v, float edge, int lane) {   // value at col c-1
    float u = __shfl_up(v.w, 1, 64);
    if (lane == 0) u = edge;
    return (f4){u, v.x, v.y, v.z};
}
__device__ __forceinline__ f4 shlf(f4 v, float edge, int lane) {   // value at col c+1
    float d = __shfl_down(v.x, 1, 64);
    if (lane == 63) d = edge;
    return (f4){v.y, v.z, v.w, d};
}
__device__ __forceinline__ i4 shri(i4 v, int edge, int lane) {
    int u = __shfl_up(v.w, 1, 64);
    if (lane == 0) u = edge;
    return (i4){u, v.x, v.y, v.z};
}
__device__ __forceinline__ i4 shli(i4 v, int edge, int lane) {
    int d = __shfl_down(v.x, 1, 64);
    if (lane == 63) d = edge;
    return (i4){v.y, v.z, v.w, d};
}

__global__ __launch_bounds__(256) void connect_loss_main(
    const float* __restrict__ cm,   // (B,8,H,W) f32
    const int*   __restrict__ tg,   // (B,1,H,W) i32
    float*       __restrict__ ws)   // per-block partials ws[k*NBLK + blk]
{
    const int lane = threadIdx.x & 63;
    const int gw   = blockIdx.x * 4 + (threadIdx.x >> 6);    // half-row id, 0..8191
    const int half = gw & 1;
    const int rowIdx = gw >> 1;                              // 0..4095
    const int r  = rowIdx & (Hn - 1);
    const int b  = rowIdx >> 9;
    const int w0 = half * 256;
    const int c0 = w0 + lane * 4;

    const float* cmb  = cm + (size_t)b * 8 * HWn;
    const int*   tgb  = tg + (size_t)b * HWn;
    const float* rowp = cmb + (size_t)r * Wn;
    const float* rowm = rowp - Wn;                           // valid iff hasUp
    const float* rowq = rowp + Wn;                           // valid iff hasDn
    const bool hasUp = (r > 0), hasDn = (r < Hn - 1);        // wave-uniform

    // ---------- issue the ENTIRE load batch ----------
    f4 xo0 = *(const f4*)(rowp + (size_t)0 * HWn + c0);
    f4 xo1 = *(const f4*)(rowp + (size_t)1 * HWn + c0);
    f4 xo2 = *(const f4*)(rowp + (size_t)2 * HWn + c0);
    f4 xo3 = *(const f4*)(rowp + (size_t)3 * HWn + c0);
    f4 xo4 = *(const f4*)(rowp + (size_t)4 * HWn + c0);
    f4 xo5 = *(const f4*)(rowp + (size_t)5 * HWn + c0);
    f4 xo6 = *(const f4*)(rowp + (size_t)6 * HWn + c0);
    f4 xo7 = *(const f4*)(rowp + (size_t)7 * HWn + c0);

    f4 xm5 = {0,0,0,0}, xm6 = {0,0,0,0}, xm7 = {0,0,0,0};
    f4 xp0 = {0,0,0,0}, xp1 = {0,0,0,0}, xp2 = {0,0,0,0};
    i4 tm = {0,0,0,0}, tp = {0,0,0,0};
    if (hasUp) {
        xm5 = *(const f4*)(rowm + (size_t)5 * HWn + c0);
        xm6 = *(const f4*)(rowm + (size_t)6 * HWn + c0);
        xm7 = *(const f4*)(rowm + (size_t)7 * HWn + c0);
        tm  = *(const i4*)(tgb + (size_t)(r - 1) * Wn + c0);
    }
    if (hasDn) {
        xp0 = *(const f4*)(rowq + (size_t)0 * HWn + c0);
        xp1 = *(const f4*)(rowq + (size_t)1 * HWn + c0);
        xp2 = *(const f4*)(rowq + (size_t)2 * HWn + c0);
        tp  = *(const i4*)(tgb + (size_t)(r + 1) * Wn + c0);
    }
    i4 tt = *(const i4*)(tgb + (size_t)r * Wn + c0);

    // wave-uniform edge-column raw values (logits; exp applied after the pin)
    float lLt = 1e9f, lLm = 1e9f, lLp = 1e9f, lRt = 1e9f, lRm = 1e9f, lRp = 1e9f;
    int   tLt = 0, tLm = 0, tLp = 0, tRt = 0, tRm = 0, tRp = 0;
    if (half == 1) {                                         // left neighbor col = 255
        lLt = rowp[(size_t)4 * HWn + 255];  tLt = tgb[(size_t)r * Wn + 255];
        if (hasUp) { lLm = rowm[(size_t)7 * HWn + 255]; tLm = tgb[(size_t)(r - 1) * Wn + 255]; }
        if (hasDn) { lLp = rowq[(size_t)2 * HWn + 255]; tLp = tgb[(size_t)(r + 1) * Wn + 255]; }
    } else {                                                 // right neighbor col = 256
        lRt = rowp[(size_t)3 * HWn + 256];  tRt = tgb[(size_t)r * Wn + 256];
        if (hasUp) { lRm = rowm[(size_t)5 * HWn + 256]; tRm = tgb[(size_t)(r - 1) * Wn + 256]; }
        if (hasDn) { lRp = rowq[(size_t)0 * HWn + 256]; tRp = tgb[(size_t)(r + 1) * Wn + 256]; }
    }

    // single pin: all loads above must be materialized here -> full-batch issue,
    // ONE s_waitcnt, then pure compute (defeats IR-level load sinking)
    asm volatile("" : "+v"(xo0), "+v"(xo1), "+v"(xo2), "+v"(xo3),
                      "+v"(xo4), "+v"(xo5), "+v"(xo6), "+v"(xo7),
                      "+v"(xm5), "+v"(xm6), "+v"(xm7),
                      "+v"(xp0), "+v"(xp1), "+v"(xp2),
                      "+v"(tt), "+v"(tm), "+v"(tp),
                      "+v"(lLt), "+v"(lLm), "+v"(lLp),
                      "+v"(lRt), "+v"(lRm), "+v"(lRp));

    // ---------- e = exp(-x) ----------
    const float eLt = (half == 1) ? __expf(-lLt) : BIGE;
    const float eLm = (half == 1 && hasUp) ? __expf(-lLm) : BIGE;
    const float eLp = (half == 1 && hasDn) ? __expf(-lLp) : BIGE;
    const float eRt = (half == 0) ? __expf(-lRt) : BIGE;
    const float eRm = (half == 0 && hasUp) ? __expf(-lRm) : BIGE;
    const float eRp = (half == 0 && hasDn) ? __expf(-lRp) : BIGE;

    f4 xo[8] = {xo0, xo1, xo2, xo3, xo4, xo5, xo6, xo7};
    f4 eo[8];
    #pragma unroll
    for (int ch = 0; ch < 8; ++ch) {
        #pragma unroll
        for (int j = 0; j < 4; ++j) eo[ch][j] = __expf(-xo[ch][j]);
    }
    f4 em5, em6, em7, ep0, ep1, ep2;
    if (hasUp) {
        #pragma unroll
        for (int j = 0; j < 4; ++j) {
            em5[j] = __expf(-xm5[j]); em6[j] = __expf(-xm6[j]); em7[j] = __expf(-xm7[j]);
        }
    } else em5 = em6 = em7 = (f4){BIGE, BIGE, BIGE, BIGE};
    if (hasDn) {
        #pragma unroll
        for (int j = 0; j < 4; ++j) {
            ep0[j] = __expf(-xp0[j]); ep1[j] = __expf(-xp1[j]); ep2[j] = __expf(-xp2[j]);
        }
    } else ep0 = ep1 = ep2 = (f4){BIGE, BIGE, BIGE, BIGE};

    // ---------- pair loop in E-space: E = e + en + e*en; vote = 1/(1+E) ----------
    f4 Emin = {3.4e38f, 3.4e38f, 3.4e38f, 3.4e38f};
    f4 Emax = {0.f, 0.f, 0.f, 0.f};
    int cnt[4] = {0, 0, 0, 0};
    float sx = 0.f;

    #define PAIR(i, ENX, TNX)                                            \
    {                                                                    \
        const f4 enx = (ENX);                                            \
        const i4 tnx = (TNX);                                            \
        _Pragma("unroll")                                                \
        for (int j = 0; j < 4; ++j) {                                    \
            const float E = __builtin_fmaf(eo[i][j], enx[j],             \
                                           eo[i][j] + enx[j]);           \
            Emin[j] = fminf(Emin[j], E);                                 \
            Emax[j] = fmaxf(Emax[j], E);                                 \
            const bool ct = (tt[j] != 0) & (tnx[j] != 0);                \
            cnt[j] += ct ? 1 : 0;                                        \
            sx += ct ? 0.f : xo[i][j];                                   \
        }                                                                \
    }
    PAIR(3, shrf(eo[4], eLt, lane), shri(tt, tLt, lane))   // ch4 @ (r, c-1)
    PAIR(4, shlf(eo[3], eRt, lane), shli(tt, tRt, lane))   // ch3 @ (r, c+1)
    PAIR(0, shrf(em7, eLm, lane),   shri(tm, tLm, lane))   // ch7 @ (r-1, c-1)
    PAIR(1, em6,                    tm)                    // ch6 @ (r-1, c)
    PAIR(2, shlf(em5, eRm, lane),   shli(tm, tRm, lane))   // ch5 @ (r-1, c+1)
    PAIR(5, shrf(ep2, eLp, lane),   shri(tp, tLp, lane))   // ch2 @ (r+1, c-1)
    PAIR(6, ep1,                    tp)                    // ch1 @ (r+1, c)
    PAIR(7, shlf(ep0, eRp, lane),   shli(tp, tRp, lane))   // ch0 @ (r+1, c+1)
    #undef PAIR

    // ---------- per-pixel tail: 3 logs per pixel ----------
    float s_logsx = sx, s_bimap = 0.f, s_edge = 0.f,
          s_inter = 0.f, s_fp = 0.f, s_t = 0.f;
    #pragma unroll
    for (int j = 0; j < 4; ++j) {
        // sum_i log p_i = -log prod_i (1+e_i)
        const float Pr = (((1.f + eo[0][j]) * (1.f + eo[1][j])) *
                          ((1.f + eo[2][j]) * (1.f + eo[3][j]))) *
                         (((1.f + eo[4][j]) * (1.f + eo[5][j])) *
                          ((1.f + eo[6][j]) * (1.f + eo[7][j])));
        s_logsx += __logf(Pr);

        const float Em = Emin[j], EM = Emax[j];
        const float vm = __builtin_amdgcn_rcpf(1.0f + Em);       // vmax
        s_bimap += __logf((tt[j] != 0) ? vm : Em * vm);          // t?log(vmax):log(1-vmax)
        const float vM = __builtin_amdgcn_rcpf(1.0f + EM);
        const bool eg = (cnt[j] > 0) & (cnt[j] < 8);
        s_edge += __logf(eg ? EM * vM : 1.0f);                   // log(1-vmin) on edge px
        s_fp    += vm;
        s_inter += (tt[j] != 0) ? vm : 0.f;
        s_t     += (float)tt[j];
    }

    // ---------- wave tree reduce, LDS combine, per-block plain store ----------
    float vals[6] = {s_logsx, s_bimap, s_edge, s_inter, s_fp, s_t};
    #pragma unroll
    for (int k = 0; k < 6; ++k) {
        float v = vals[k];
        #pragma unroll
        for (int off = 32; off > 0; off >>= 1) v += __shfl_down(v, off, 64);
        vals[k] = v;
    }
    __shared__ float bs[6];
    if (threadIdx.x < 6) bs[threadIdx.x] = 0.0f;
    __syncthreads();
    if ((threadIdx.x & 63) == 0) {
        #pragma unroll
        for (int k = 0; k < 6; ++k) atomicAdd(&bs[k], vals[k]);
    }
    __syncthreads();
    if (threadIdx.x < 6)
        ws[threadIdx.x * NBLK + blockIdx.x] = bs[threadIdx.x];
}

// single-block reduce of 6 x NBLK partials + final loss
__global__ __launch_bounds__(256) void connect_loss_reduce(
    const float* __restrict__ ws, float* __restrict__ out)
{
    float acc[6];
    #pragma unroll
    for (int k = 0; k < 6; ++k) {
        const f4* p = (const f4*)(ws + k * NBLK + threadIdx.x * 8);
        const f4 a = p[0], b2 = p[1];                   // 256*8 = 2048 = NBLK
        acc[k] = (a.x + a.y) + (a.z + a.w) + (b2.x + b2.y) + (b2.z + b2.w);
    }
    #pragma unroll
    for (int k = 0; k < 6; ++k) {
        float v = acc[k];
        #pragma unroll
        for (int off = 32; off > 0; off >>= 1) v += __shfl_down(v, off, 64);
        acc[k] = v;
    }
    __shared__ float bs[6];
    if (threadIdx.x < 6) bs[threadIdx.x] = 0.0f;
    __syncthreads();
    if ((threadIdx.x & 63) == 0) {
        #pragma unroll
        for (int k = 0; k < 6; ++k) atomicAdd(&bs[k], acc[k]);
    }
    __syncthreads();
    if (threadIdx.x == 0) {
        // bs[0] = sum(log(1+e)) + sum((1-ct)x) = -sum(conn BCE log-terms)
        const float conn_l  =  bs[0] / (float)(8 * NPIX);
        const float bimap_l = -bs[1] / (float)NPIX;
        const float edge_l  = -bs[2] / (float)NPIX;
        const float dice_l  = 1.0f - (2.0f * bs[3] + 1.0f) / (bs[4] + bs[5] + 1.0f);
        out[0] = conn_l + bimap_l + edge_l + dice_l;
    }
}

extern "C" void kernel_launch(void* const* d_in, const int* in_sizes, int n_in,
                              void* d_out, int out_size, void* d_ws, size_t ws_size,
                              hipStream_t stream) {
    const float* cm = (const float*)d_in[0];      // c_map (B,8,H,W) f32
    const int*   tg = (const int*)d_in[3];        // target (B,1,H,W) i32
    float* ws  = (float*)d_ws;                    // 6*NBLK floats (48 KB)
    float* out = (float*)d_out;

    connect_loss_main<<<NBLK, 256, 0, stream>>>(cm, tg, ws);
    connect_loss_reduce<<<1, 256, 0, stream>>>(ws, out);
}

// Round 16
// 24.224 us; speedup vs baseline: 1.3675x; 1.1150x over previous
//
#include <hip/hip_runtime.h>

constexpr int Bn  = 8;
constexpr int Hn  = 512;
constexpr int Wn  = 512;
constexpr int HWn = Hn * Wn;        // 262144
constexpr int NPIX = Bn * HWn;      // 2097152
constexpr int NBLK = 2048;          // 4 waves/block; wave = half-row, 4 px/lane
constexpr float BIGE = 1e30f;       // missing neighbor: vote==0 exactly in f32 logs

typedef float f4 __attribute__((ext_vector_type(4)));
typedef int   i4 __attribute__((ext_vector_type(4)));

// channel order: [down_right, down, down_left, right, left, up_right, up, up_left]
// conn_t[i][r,c] = t[r,c]*t[r-dy_i,c-dx_i]; vote[i][r,c] = p_i[r,c]*p_{7-i}[r-dy_i,c-dx_i]
// dy = {1,1,1,0,0,-1,-1,-1}, dx = {1,0,-1,1,-1,1,0,-1}

__device__ __forceinline__ f4 shrf(f4 v, float edge, int lane) {   // value at col c-1
    float u = __shfl_up(v.w, 1, 64);
    if (lane == 0) u = edge;
    return (f4){u, v.x, v.y, v.z};
}
__device__ __forceinline__ f4 shlf(f4 v, float edge, int lane) {   // value at col c+1
    float d = __shfl_down(v.x, 1, 64);
    if (lane == 63) d = edge;
    return (f4){v.y, v.z, v.w, d};
}
__device__ __forceinline__ i4 shri(i4 v, int edge, int lane) {
    int u = __shfl_up(v.w, 1, 64);
    if (lane == 0) u = edge;
    return (i4){u, v.x, v.y, v.z};
}
__device__ __forceinline__ i4 shli(i4 v, int edge, int lane) {
    int d = __shfl_down(v.x, 1, 64);
    if (lane == 63) d = edge;
    return (i4){v.y, v.z, v.w, d};
}

__global__ __launch_bounds__(256) void connect_loss_main(
    const float* __restrict__ cm,   // (B,8,H,W) f32
    const int*   __restrict__ tg,   // (B,1,H,W) i32
    float*       __restrict__ ws)   // per-block partials ws[k*NBLK + blk]
{
    const int lane = threadIdx.x & 63;
    // XCD-aware swizzle: dispatch round-robins blocks over 8 XCDs; remap so each
    // XCD owns a contiguous 512-row band -> the 3x row-reuse (r-1,r,r+1) is L2-local.
    // Bijective since NBLK % 8 == 0.
    const int vb   = (blockIdx.x & 7) * (NBLK / 8) + (blockIdx.x >> 3);
    const int gw   = vb * 4 + (threadIdx.x >> 6);            // half-row id, 0..8191
    const int half = gw & 1;
    const int rowIdx = gw >> 1;                              // 0..4095
    const int r  = rowIdx & (Hn - 1);
    const int b  = rowIdx >> 9;
    const int w0 = half * 256;
    const int c0 = w0 + lane * 4;

    const float* cmb  = cm + (size_t)b * 8 * HWn;
    const int*   tgb  = tg + (size_t)b * HWn;
    const float* rowp = cmb + (size_t)r * Wn;
    const float* rowm = rowp - Wn;                           // valid iff hasUp
    const float* rowq = rowp + Wn;                           // valid iff hasDn
    const bool hasUp = (r > 0), hasDn = (r < Hn - 1);        // wave-uniform

    // ---------- issue the ENTIRE load batch ----------
    f4 xo0 = *(const f4*)(rowp + (size_t)0 * HWn + c0);
    f4 xo1 = *(const f4*)(rowp + (size_t)1 * HWn + c0);
    f4 xo2 = *(const f4*)(rowp + (size_t)2 * HWn + c0);
    f4 xo3 = *(const f4*)(rowp + (size_t)3 * HWn + c0);
    f4 xo4 = *(const f4*)(rowp + (size_t)4 * HWn + c0);
    f4 xo5 = *(const f4*)(rowp + (size_t)5 * HWn + c0);
    f4 xo6 = *(const f4*)(rowp + (size_t)6 * HWn + c0);
    f4 xo7 = *(const f4*)(rowp + (size_t)7 * HWn + c0);

    f4 xm5 = {0,0,0,0}, xm6 = {0,0,0,0}, xm7 = {0,0,0,0};
    f4 xp0 = {0,0,0,0}, xp1 = {0,0,0,0}, xp2 = {0,0,0,0};
    i4 tm = {0,0,0,0}, tp = {0,0,0,0};
    if (hasUp) {
        xm5 = *(const f4*)(rowm + (size_t)5 * HWn + c0);
        xm6 = *(const f4*)(rowm + (size_t)6 * HWn + c0);
        xm7 = *(const f4*)(rowm + (size_t)7 * HWn + c0);
        tm  = *(const i4*)(tgb + (size_t)(r - 1) * Wn + c0);
    }
    if (hasDn) {
        xp0 = *(const f4*)(rowq + (size_t)0 * HWn + c0);
        xp1 = *(const f4*)(rowq + (size_t)1 * HWn + c0);
        xp2 = *(const f4*)(rowq + (size_t)2 * HWn + c0);
        tp  = *(const i4*)(tgb + (size_t)(r + 1) * Wn + c0);
    }
    i4 tt = *(const i4*)(tgb + (size_t)r * Wn + c0);

    // wave-uniform edge-column raw values (logits; exp applied after the pin)
    float lLt = 1e9f, lLm = 1e9f, lLp = 1e9f, lRt = 1e9f, lRm = 1e9f, lRp = 1e9f;
    int   tLt = 0, tLm = 0, tLp = 0, tRt = 0, tRm = 0, tRp = 0;
    if (half == 1) {                                         // left neighbor col = 255
        lLt = rowp[(size_t)4 * HWn + 255];  tLt = tgb[(size_t)r * Wn + 255];
        if (hasUp) { lLm = rowm[(size_t)7 * HWn + 255]; tLm = tgb[(size_t)(r - 1) * Wn + 255]; }
        if (hasDn) { lLp = rowq[(size_t)2 * HWn + 255]; tLp = tgb[(size_t)(r + 1) * Wn + 255]; }
    } else {                                                 // right neighbor col = 256
        lRt = rowp[(size_t)3 * HWn + 256];  tRt = tgb[(size_t)r * Wn + 256];
        if (hasUp) { lRm = rowm[(size_t)5 * HWn + 256]; tRm = tgb[(size_t)(r - 1) * Wn + 256]; }
        if (hasDn) { lRp = rowq[(size_t)0 * HWn + 256]; tRp = tgb[(size_t)(r + 1) * Wn + 256]; }
    }

    // single pin: all loads above must be materialized here -> full-batch issue,
    // ONE s_waitcnt, then pure compute (defeats IR-level load sinking)
    asm volatile("" : "+v"(xo0), "+v"(xo1), "+v"(xo2), "+v"(xo3),
                      "+v"(xo4), "+v"(xo5), "+v"(xo6), "+v"(xo7),
                      "+v"(xm5), "+v"(xm6), "+v"(xm7),
                      "+v"(xp0), "+v"(xp1), "+v"(xp2),
                      "+v"(tt), "+v"(tm), "+v"(tp),
                      "+v"(lLt), "+v"(lLm), "+v"(lLp),
                      "+v"(lRt), "+v"(lRm), "+v"(lRp));

    // ---------- e = exp(-x) ----------
    const float eLt = (half == 1) ? __expf(-lLt) : BIGE;
    const float eLm = (half == 1 && hasUp) ? __expf(-lLm) : BIGE;
    const float eLp = (half == 1 && hasDn) ? __expf(-lLp) : BIGE;
    const float eRt = (half == 0) ? __expf(-lRt) : BIGE;
    const float eRm = (half == 0 && hasUp) ? __expf(-lRm) : BIGE;
    const float eRp = (half == 0 && hasDn) ? __expf(-lRp) : BIGE;

    f4 xo[8] = {xo0, xo1, xo2, xo3, xo4, xo5, xo6, xo7};
    f4 eo[8];
    #pragma unroll
    for (int ch = 0; ch < 8; ++ch) {
        #pragma unroll
        for (int j = 0; j < 4; ++j) eo[ch][j] = __expf(-xo[ch][j]);
    }
    f4 em5, em6, em7, ep0, ep1, ep2;
    if (hasUp) {
        #pragma unroll
        for (int j = 0; j < 4; ++j) {
            em5[j] = __expf(-xm5[j]); em6[j] = __expf(-xm6[j]); em7[j] = __expf(-xm7[j]);
        }
    } else em5 = em6 = em7 = (f4){BIGE, BIGE, BIGE, BIGE};
    if (hasDn) {
        #pragma unroll
        for (int j = 0; j < 4; ++j) {
            ep0[j] = __expf(-xp0[j]); ep1[j] = __expf(-xp1[j]); ep2[j] = __expf(-xp2[j]);
        }
    } else ep0 = ep1 = ep2 = (f4){BIGE, BIGE, BIGE, BIGE};

    // ---------- pair loop in E-space: E = e + en + e*en; vote = 1/(1+E) ----------
    f4 Emin = {3.4e38f, 3.4e38f, 3.4e38f, 3.4e38f};
    f4 Emax = {0.f, 0.f, 0.f, 0.f};
    int cnt[4] = {0, 0, 0, 0};
    float sx = 0.f;

    #define PAIR(i, ENX, TNX)                                            \
    {                                                                    \
        const f4 enx = (ENX);                                            \
        const i4 tnx = (TNX);                                            \
        _Pragma("unroll")                                                \
        for (int j = 0; j < 4; ++j) {                                    \
            const float E = __builtin_fmaf(eo[i][j], enx[j],             \
                                           eo[i][j] + enx[j]);           \
            Emin[j] = fminf(Emin[j], E);                                 \
            Emax[j] = fmaxf(Emax[j], E);                                 \
            const bool ct = (tt[j] != 0) & (tnx[j] != 0);                \
            cnt[j] += ct ? 1 : 0;                                        \
            sx += ct ? 0.f : xo[i][j];                                   \
        }                                                                \
    }
    PAIR(3, shrf(eo[4], eLt, lane), shri(tt, tLt, lane))   // ch4 @ (r, c-1)
    PAIR(4, shlf(eo[3], eRt, lane), shli(tt, tRt, lane))   // ch3 @ (r, c+1)
    PAIR(0, shrf(em7, eLm, lane),   shri(tm, tLm, lane))   // ch7 @ (r-1, c-1)
    PAIR(1, em6,                    tm)                    // ch6 @ (r-1, c)
    PAIR(2, shlf(em5, eRm, lane),   shli(tm, tRm, lane))   // ch5 @ (r-1, c+1)
    PAIR(5, shrf(ep2, eLp, lane),   shri(tp, tLp, lane))   // ch2 @ (r+1, c-1)
    PAIR(6, ep1,                    tp)                    // ch1 @ (r+1, c)
    PAIR(7, shlf(ep0, eRp, lane),   shli(tp, tRp, lane))   // ch0 @ (r+1, c+1)
    #undef PAIR

    // ---------- per-pixel tail: 3 logs per pixel ----------
    float s_logsx = sx, s_bimap = 0.f, s_edge = 0.f,
          s_inter = 0.f, s_fp = 0.f, s_t = 0.f;
    #pragma unroll
    for (int j = 0; j < 4; ++j) {
        // sum_i log p_i = -log prod_i (1+e_i)
        const float Pr = (((1.f + eo[0][j]) * (1.f + eo[1][j])) *
                          ((1.f + eo[2][j]) * (1.f + eo[3][j]))) *
                         (((1.f + eo[4][j]) * (1.f + eo[5][j])) *
                          ((1.f + eo[6][j]) * (1.f + eo[7][j])));
        s_logsx += __logf(Pr);

        const float Em = Emin[j], EM = Emax[j];
        const float vm = __builtin_amdgcn_rcpf(1.0f + Em);       // vmax
        s_bimap += __logf((tt[j] != 0) ? vm : Em * vm);          // t?log(vmax):log(1-vmax)
        const float vM = __builtin_amdgcn_rcpf(1.0f + EM);
        const bool eg = (cnt[j] > 0) & (cnt[j] < 8);
        s_edge += __logf(eg ? EM * vM : 1.0f);                   // log(1-vmin) on edge px
        s_fp    += vm;
        s_inter += (tt[j] != 0) ? vm : 0.f;
        s_t     += (float)tt[j];
    }

    // ---------- wave tree reduce, LDS combine, per-block plain store ----------
    float vals[6] = {s_logsx, s_bimap, s_edge, s_inter, s_fp, s_t};
    #pragma unroll
    for (int k = 0; k < 6; ++k) {
        float v = vals[k];
        #pragma unroll
        for (int off = 32; off > 0; off >>= 1) v += __shfl_down(v, off, 64);
        vals[k] = v;
    }
    __shared__ float bs[6];
    if (threadIdx.x < 6) bs[threadIdx.x] = 0.0f;
    __syncthreads();
    if ((threadIdx.x & 63) == 0) {
        #pragma unroll
        for (int k = 0; k < 6; ++k) atomicAdd(&bs[k], vals[k]);
    }
    __syncthreads();
    if (threadIdx.x < 6)
        ws[threadIdx.x * NBLK + blockIdx.x] = bs[threadIdx.x];
}

// single-block reduce of 6 x NBLK partials + final loss
__global__ __launch_bounds__(256) void connect_loss_reduce(
    const float* __restrict__ ws, float* __restrict__ out)
{
    float acc[6];
    #pragma unroll
    for (int k = 0; k < 6; ++k) {
        const f4* p = (const f4*)(ws + k * NBLK + threadIdx.x * 8);
        const f4 a = p[0], b2 = p[1];                   // 256*8 = 2048 = NBLK
        acc[k] = (a.x + a.y) + (a.z + a.w) + (b2.x + b2.y) + (b2.z + b2.w);
    }
    #pragma unroll
    for (int k = 0; k < 6; ++k) {
        float v = acc[k];
        #pragma unroll
        for (int off = 32; off > 0; off >>= 1) v += __shfl_down(v, off, 64);
        acc[k] = v;
    }
    __shared__ float bs[6];
    if (threadIdx.x < 6) bs[threadIdx.x] = 0.0f;
    __syncthreads();
    if ((threadIdx.x & 63) == 0) {
        #pragma unroll
        for (int k = 0; k < 6; ++k) atomicAdd(&bs[k], acc[k]);
    }
    __syncthreads();
    if (threadIdx.x == 0) {
        // bs[0] = sum(log(1+e)) + sum((1-ct)x) = -sum(conn BCE log-terms)
        const float conn_l  =  bs[0] / (float)(8 * NPIX);
        const float bimap_l = -bs[1] / (float)NPIX;
        const float edge_l  = -bs[2] / (float)NPIX;
        const float dice_l  = 1.0f - (2.0f * bs[3] + 1.0f) / (bs[4] + bs[5] + 1.0f);
        out[0] = conn_l + bimap_l + edge_l + dice_l;
    }
}

extern "C" void kernel_launch(void* const* d_in, const int* in_sizes, int n_in,
                              void* d_out, int out_size, void* d_ws, size_t ws_size,
                              hipStream_t stream) {
    const float* cm = (const float*)d_in[0];      // c_map (B,8,H,W) f32
    const int*   tg = (const int*)d_in[3];        // target (B,1,H,W) i32
    float* ws  = (float*)d_ws;                    // 6*NBLK floats (48 KB)
    float* out = (float*)d_out;

    connect_loss_main<<<NBLK, 256, 0, stream>>>(cm, tg, ws);
    connect_loss_reduce<<<1, 256, 0, stream>>>(ws, out);
}